// Round 1
// baseline (390.751 us; speedup 1.0000x reference)
//
#include <hip/hip_runtime.h>
#include <math.h>

// DiscriminativeLoss: embeddings (8,16,512,512) f32, instance_masks (8,512,512) i32 in [0,33)
// out: 4 f32 [total, var, dist, reg]

#define B 8
#define E 16
#define HW (512*512)
#define K 33
#define BLK 256
#define BPI 64                 // blocks per image
#define VPB (HW / 4 / BPI)     // float4-pixel groups per block = 1024

__device__ __forceinline__ float atomAddF(float* p, float v) {
  return unsafeAtomicAdd(p, v);   // native ds_add_f32 / global_atomic_add_f32 on gfx950
}

// ---------------- Pass 1: per-image segment sums + counts ----------------
__global__ __launch_bounds__(BLK) void pass1_kernel(
    const float* __restrict__ emb, const int* __restrict__ mask,
    float* __restrict__ sums /*[B][K][E]*/, int* __restrict__ counts /*[B][K]*/) {
  // lsum layout [E][K]: addr e*33+id -> 33 ids spread over 32 banks (~2-way, free)
  __shared__ float lsum[E][K];
  __shared__ int   lcnt[K];
  const int b = blockIdx.y;
  const int t = threadIdx.x;

  for (int i = t; i < E * K; i += BLK) (&lsum[0][0])[i] = 0.f;
  if (t < K) lcnt[t] = 0;
  __syncthreads();

  const int4* maskv = (const int4*)(mask + (size_t)b * HW);
  const int v0 = blockIdx.x * VPB;

#pragma unroll 1
  for (int v = v0 + t; v < v0 + VPB; v += BLK) {
    const int4 id = maskv[v];
    atomicAdd(&lcnt[id.x], 1);
    atomicAdd(&lcnt[id.y], 1);
    atomicAdd(&lcnt[id.z], 1);
    atomicAdd(&lcnt[id.w], 1);
#pragma unroll
    for (int e = 0; e < E; ++e) {
      const float4 x = ((const float4*)(emb + (size_t)(b * E + e) * HW))[v];
      atomAddF(&lsum[e][id.x], x.x);
      atomAddF(&lsum[e][id.y], x.y);
      atomAddF(&lsum[e][id.z], x.z);
      atomAddF(&lsum[e][id.w], x.w);
    }
  }
  __syncthreads();

  for (int i = t; i < E * K; i += BLK) {
    const int e = i / K, k = i - e * K;
    atomAddF(&sums[((size_t)b * K + k) * E + e], lsum[e][k]);
  }
  if (t < K) atomicAdd(&counts[b * K + t], lcnt[t]);
}

// ---------------- Pass 2: per-pixel hinge( ||x - mean[id]|| ) ----------------
__global__ __launch_bounds__(BLK) void pass2_kernel(
    const float* __restrict__ emb, const int* __restrict__ mask,
    const float* __restrict__ sums, const int* __restrict__ counts,
    float* __restrict__ var_per /*[B][K]*/) {
  __shared__ float mean[K][E + 1];  // pad to 17: stride coprime with 32 banks
  __shared__ float lvar[K];
  const int b = blockIdx.y;
  const int t = threadIdx.x;

  for (int i = t; i < K * E; i += BLK) {
    const int k = i / E, e = i - k * E;
    const float c  = (float)counts[b * K + k];
    const float cc = c > 1.f ? c : 1.f;
    mean[k][e] = sums[((size_t)b * K + k) * E + e] / cc;
  }
  if (t < K) lvar[t] = 0.f;
  __syncthreads();

  const int4* maskv = (const int4*)(mask + (size_t)b * HW);
  const int v0 = blockIdx.x * VPB;

#pragma unroll 1
  for (int v = v0 + t; v < v0 + VPB; v += BLK) {
    const int4 id = maskv[v];
    float d0 = 0.f, d1 = 0.f, d2 = 0.f, d3 = 0.f;
#pragma unroll
    for (int e = 0; e < E; ++e) {
      const float4 x = ((const float4*)(emb + (size_t)(b * E + e) * HW))[v];
      const float t0 = x.x - mean[id.x][e]; d0 += t0 * t0;
      const float t1 = x.y - mean[id.y][e]; d1 += t1 * t1;
      const float t2 = x.z - mean[id.z][e]; d2 += t2 * t2;
      const float t3 = x.w - mean[id.w][e]; d3 += t3 * t3;
    }
    // background (id==0) is excluded from var loss -> skip
    if (id.x) { const float d = d0 > 0.f ? sqrtf(d0) : 0.f; const float h = d - 0.5f; if (h > 0.f) atomAddF(&lvar[id.x], h * h); }
    if (id.y) { const float d = d1 > 0.f ? sqrtf(d1) : 0.f; const float h = d - 0.5f; if (h > 0.f) atomAddF(&lvar[id.y], h * h); }
    if (id.z) { const float d = d2 > 0.f ? sqrtf(d2) : 0.f; const float h = d - 0.5f; if (h > 0.f) atomAddF(&lvar[id.z], h * h); }
    if (id.w) { const float d = d3 > 0.f ? sqrtf(d3) : 0.f; const float h = d - 0.5f; if (h > 0.f) atomAddF(&lvar[id.w], h * h); }
  }
  __syncthreads();

  if (t < K) atomAddF(&var_per[b * K + t], lvar[t]);  // lvar[0] stays 0
}

// ---------------- Final: losses from sums/counts/var_per ----------------
__global__ __launch_bounds__(BLK) void final_kernel(
    const float* __restrict__ sums, const int* __restrict__ counts,
    const float* __restrict__ var_per, float* __restrict__ out) {
  __shared__ float mean[B][K][E];   // 16.9 KB
  __shared__ float vb[B], rb[B], db[B], pb[B], nb[B];
  const int t = threadIdx.x;

  if (t < B) { vb[t] = 0.f; rb[t] = 0.f; db[t] = 0.f; pb[t] = 0.f; nb[t] = 0.f; }
  for (int i = t; i < B * K * E; i += BLK) {
    const int b = i / (K * E);
    const int r = i - b * (K * E);
    const int k = r / E;
    const float c  = (float)counts[b * K + k];
    const float cc = c > 1.f ? c : 1.f;
    (&mean[0][0][0])[i] = sums[i] / cc;
  }
  __syncthreads();

  // var + reg per instance: exactly B*(K-1) = 256 entries = blockDim
  if (t < B * (K - 1)) {
    const int b = t / (K - 1);
    const int k = t - b * (K - 1) + 1;
    const int c = counts[b * K + k];
    if (c > 0) {
      atomAddF(&nb[b], 1.f);
      atomAddF(&vb[b], var_per[b * K + k] / (float)c);
      float sq = 0.f;
#pragma unroll
      for (int e = 0; e < E; ++e) { const float m = mean[b][k][e]; sq += m * m; }
      atomAddF(&rb[b], sq > 0.f ? sqrtf(sq) : 0.f);
    }
  }
  __syncthreads();

  // pairwise dist hinge over 32x32 ordered grid, keep i<j
  for (int idx = t; idx < B * 32 * 32; idx += BLK) {
    const int b = idx >> 10;
    const int p = idx & 1023;
    const int i = p >> 5;
    const int j = p & 31;
    if (i < j) {
      if (counts[b * K + 1 + i] > 0 && counts[b * K + 1 + j] > 0) {
        atomAddF(&pb[b], 1.f);
        float sq = 0.f;
#pragma unroll
        for (int e = 0; e < E; ++e) {
          const float d = mean[b][1 + i][e] - mean[b][1 + j][e];
          sq += d * d;
        }
        const float d = sq > 0.f ? sqrtf(sq) : 0.f;
        const float h = 3.0f - d;   // 2*DELTA_D - d
        if (h > 0.f) atomAddF(&db[b], h * h);
      }
    }
  }
  __syncthreads();

  if (t == 0) {
    float sv = 0.f, sd = 0.f, sr = 0.f, svalid = 0.f;
    for (int b = 0; b < B; ++b) {
      const float ni  = nb[b];
      const float nim = ni > 1.f ? ni : 1.f;
      const float var_b = vb[b] / nim;
      const float reg_b = rb[b] / nim;
      const float npm   = pb[b] > 1.f ? pb[b] : 1.f;
      const float dist_b = (ni > 1.f) ? (db[b] / npm) : 0.f;
      const float valid  = ni > 0.f ? 1.f : 0.f;
      sv += var_b * valid;
      sd += dist_b * valid;
      sr += reg_b * valid;
      svalid += valid;
    }
    const float vs = svalid > 1.f ? svalid : 1.f;
    const float var = sv / vs, dist = sd / vs, reg = sr / vs;
    out[0] = var + dist + 0.001f * reg;
    out[1] = var;
    out[2] = dist;
    out[3] = reg;
  }
}

extern "C" void kernel_launch(void* const* d_in, const int* in_sizes, int n_in,
                              void* d_out, int out_size, void* d_ws, size_t ws_size,
                              hipStream_t stream) {
  const float* emb  = (const float*)d_in[0];
  const int*   mask = (const int*)d_in[1];
  float* out = (float*)d_out;

  float* sums    = (float*)d_ws;                                       // B*K*E
  int*   counts  = (int*)((char*)d_ws + (size_t)B * K * E * 4);        // B*K
  float* var_per = (float*)((char*)d_ws + (size_t)(B * K * E + B * K) * 4);  // B*K

  const size_t zbytes = (size_t)(B * K * E + 2 * B * K) * 4;
  hipMemsetAsync(d_ws, 0, zbytes, stream);

  dim3 grid(BPI, B);
  pass1_kernel<<<grid, BLK, 0, stream>>>(emb, mask, sums, counts);
  pass2_kernel<<<grid, BLK, 0, stream>>>(emb, mask, sums, counts, var_per);
  final_kernel<<<1, BLK, 0, stream>>>(sums, counts, var_per, out);
}

// Round 2
// 389.517 us; speedup vs baseline: 1.0032x; 1.0032x over previous
//
#include <hip/hip_runtime.h>
#include <math.h>

// DiscriminativeLoss: embeddings (8,16,512,512) f32, instance_masks (8,512,512) i32 in [0,33)
// out: 4 f32 [total, var, dist, reg]
//
// Segment 0 (background) provably never affects the output (var/dist/reg all
// use segments 1..32 only), so workspace stores 32 segments; LDS keeps a
// 33rd "trash row" at index 0 so id==0 pixels need no branch.

#define B 8
#define E 16
#define HW (512*512)
#define KI 32                  // instance ids 1..32 -> rows 0..31 in workspace
#define KR 33                  // LDS rows incl. trash row 0 (indexed by raw id)
#define BLK 256
#define P1_BPI 128
#define P1_VPB (HW/4/P1_BPI)   // 512 float4-groups per block -> 2 iters/thread
#define P2_BPI 256
#define P2_VPB (HW/4/P2_BPI)   // 256 -> 1 iter/thread
#define NCOL 8                 // lane-privatization columns (c = lane & 7)
#define MPAD 20                // mean row stride: 80 B -> rows 16B-aligned for ds_read_b128

__device__ __forceinline__ float atomAddF(float* p, float v) {
  return unsafeAtomicAdd(p, v);   // native ds_add_f32 / global_atomic_add_f32
}

// ---------------- Pass 1: per-image segment sums + counts ----------------
__global__ __launch_bounds__(BLK) void pass1_kernel(
    const float* __restrict__ emb, const int* __restrict__ mask,
    float* __restrict__ sums /*[B][KI][E]*/, int* __restrict__ counts /*[B][KI]*/) {
  // [E][KR][NCOL]: addr ((e*33+id)*8+c) -> for one ds_add inst (fixed e), the
  // 8 lanes sharing column c hit banks {8k%32}+c -> ~2-way aliasing (free).
  __shared__ float lsum[E][KR][NCOL];   // 16.5 KB
  __shared__ int   lcnt[KR][NCOL];      // 1 KB
  const int b = blockIdx.y;
  const int t = threadIdx.x;
  const int c = t & (NCOL - 1);

  for (int i = t; i < E * KR * NCOL; i += BLK) (&lsum[0][0][0])[i] = 0.f;
  for (int i = t; i < KR * NCOL; i += BLK) (&lcnt[0][0])[i] = 0;
  __syncthreads();

  const int4* __restrict__ maskv = (const int4*)(mask + (size_t)b * HW);
  const float* __restrict__ embb = emb + (size_t)b * E * HW;
  const int v0 = blockIdx.x * P1_VPB;

#pragma unroll 1
  for (int v = v0 + t; v < v0 + P1_VPB; v += BLK) {
    const int4 id = maskv[v];
    float4 x[E];                 // load ALL planes first: pipelined vmcnt
#pragma unroll
    for (int e = 0; e < E; ++e) x[e] = ((const float4*)(embb + (size_t)e * HW))[v];
    atomicAdd(&lcnt[id.x][c], 1);
    atomicAdd(&lcnt[id.y][c], 1);
    atomicAdd(&lcnt[id.z][c], 1);
    atomicAdd(&lcnt[id.w][c], 1);
#pragma unroll
    for (int e = 0; e < E; ++e) {
      atomAddF(&lsum[e][id.x][c], x[e].x);
      atomAddF(&lsum[e][id.y][c], x[e].y);
      atomAddF(&lsum[e][id.z][c], x[e].z);
      atomAddF(&lsum[e][id.w][c], x[e].w);
    }
  }
  __syncthreads();

  for (int i = t; i < E * KI; i += BLK) {      // 512 entries, 2/thread
    const int e = i >> 5, k = i & 31;          // k -> LDS row k+1
    float s = 0.f;
#pragma unroll
    for (int cc = 0; cc < NCOL; ++cc) s += lsum[e][k + 1][cc];
    atomAddF(&sums[((size_t)b * KI + k) * E + e], s);
  }
  if (t < KI) {
    int s = 0;
#pragma unroll
    for (int cc = 0; cc < NCOL; ++cc) s += lcnt[t + 1][cc];
    atomicAdd(&counts[b * KI + t], s);
  }
}

// ---------------- Pass 2: per-pixel hinge( ||x - mean[id]|| ) ----------------
__global__ __launch_bounds__(BLK) void pass2_kernel(
    const float* __restrict__ emb, const int* __restrict__ mask,
    const float* __restrict__ sums, const int* __restrict__ counts,
    float* __restrict__ var_per /*[B][KI]*/) {
  __shared__ float mean[KR][MPAD];   // row 0 = zeros (id==0 results discarded)
  __shared__ float lvar[KR][NCOL];
  const int b = blockIdx.y;
  const int t = threadIdx.x;
  const int c = t & (NCOL - 1);

  for (int i = t; i < KR * MPAD; i += BLK) {
    const int k = i / MPAD, e = i - k * MPAD;
    float m = 0.f;
    if (k >= 1 && e < E) {
      const int cnt = counts[b * KI + (k - 1)];
      const float cc = cnt > 1 ? (float)cnt : 1.f;
      m = sums[((size_t)b * KI + (k - 1)) * E + e] / cc;
    }
    mean[k][e] = m;
  }
  for (int i = t; i < KR * NCOL; i += BLK) (&lvar[0][0])[i] = 0.f;
  __syncthreads();

  const int4* __restrict__ maskv = (const int4*)(mask + (size_t)b * HW);
  const float* __restrict__ embb = emb + (size_t)b * E * HW;
  const int v0 = blockIdx.x * P2_VPB;

#pragma unroll 1
  for (int v = v0 + t; v < v0 + P2_VPB; v += BLK) {
    const int4 id = maskv[v];
    float4 x[E];
#pragma unroll
    for (int e = 0; e < E; ++e) x[e] = ((const float4*)(embb + (size_t)e * HW))[v];
    float d0 = 0.f, d1 = 0.f, d2 = 0.f, d3 = 0.f;
#pragma unroll
    for (int j = 0; j < 4; ++j) {
      const float4 m0 = *(const float4*)&mean[id.x][4 * j];
      const float4 m1 = *(const float4*)&mean[id.y][4 * j];
      const float4 m2 = *(const float4*)&mean[id.z][4 * j];
      const float4 m3 = *(const float4*)&mean[id.w][4 * j];
      const float4 a0 = x[4 * j + 0], a1 = x[4 * j + 1];
      const float4 a2 = x[4 * j + 2], a3 = x[4 * j + 3];
      float u;
      u = a0.x - m0.x; d0 += u * u;  u = a1.x - m0.y; d0 += u * u;
      u = a2.x - m0.z; d0 += u * u;  u = a3.x - m0.w; d0 += u * u;
      u = a0.y - m1.x; d1 += u * u;  u = a1.y - m1.y; d1 += u * u;
      u = a2.y - m1.z; d1 += u * u;  u = a3.y - m1.w; d1 += u * u;
      u = a0.z - m2.x; d2 += u * u;  u = a1.z - m2.y; d2 += u * u;
      u = a2.z - m2.z; d2 += u * u;  u = a3.z - m2.w; d2 += u * u;
      u = a0.w - m3.x; d3 += u * u;  u = a1.w - m3.y; d3 += u * u;
      u = a2.w - m3.z; d3 += u * u;  u = a3.w - m3.w; d3 += u * u;
    }
    float h;  // branch-free hinge; id==0 rows land in trash row 0
    h = fmaxf(sqrtf(d0) - 0.5f, 0.f); atomAddF(&lvar[id.x][c], h * h);
    h = fmaxf(sqrtf(d1) - 0.5f, 0.f); atomAddF(&lvar[id.y][c], h * h);
    h = fmaxf(sqrtf(d2) - 0.5f, 0.f); atomAddF(&lvar[id.z][c], h * h);
    h = fmaxf(sqrtf(d3) - 0.5f, 0.f); atomAddF(&lvar[id.w][c], h * h);
  }
  __syncthreads();

  if (t < KI) {
    float s = 0.f;
#pragma unroll
    for (int cc = 0; cc < NCOL; ++cc) s += lvar[t + 1][cc];
    atomAddF(&var_per[b * KI + t], s);
  }
}

// ---------------- Final: losses from sums/counts/var_per ----------------
__global__ __launch_bounds__(BLK) void final_kernel(
    const float* __restrict__ sums, const int* __restrict__ counts,
    const float* __restrict__ var_per, float* __restrict__ out) {
  __shared__ float mean[B][KI][E];   // 16 KB
  __shared__ float vb[B], rb[B], db[B], pb[B], nb[B];
  const int t = threadIdx.x;

  if (t < B) { vb[t] = 0.f; rb[t] = 0.f; db[t] = 0.f; pb[t] = 0.f; nb[t] = 0.f; }
  for (int i = t; i < B * KI * E; i += BLK) {
    const int bb = i / (KI * E);
    const int k = (i / E) & 31;
    const int cnt = counts[bb * KI + k];
    const float cc = cnt > 1 ? (float)cnt : 1.f;
    (&mean[0][0][0])[i] = sums[i] / cc;
  }
  __syncthreads();

  // var + reg per instance: B*KI = 256 entries = blockDim
  if (t < B * KI) {
    const int bb = t >> 5, k = t & 31;
    const int cnt = counts[bb * KI + k];
    if (cnt > 0) {
      atomAddF(&nb[bb], 1.f);
      atomAddF(&vb[bb], var_per[bb * KI + k] / (float)cnt);
      float sq = 0.f;
#pragma unroll
      for (int e = 0; e < E; ++e) { const float m = mean[bb][k][e]; sq += m * m; }
      atomAddF(&rb[bb], sq > 0.f ? sqrtf(sq) : 0.f);
    }
  }
  __syncthreads();

  // pairwise dist hinge over 32x32 ordered grid, keep i<j
  for (int idx = t; idx < B * KI * KI; idx += BLK) {
    const int bb = idx >> 10;
    const int p = idx & 1023;
    const int i = p >> 5;
    const int j = p & 31;
    if (i < j && counts[bb * KI + i] > 0 && counts[bb * KI + j] > 0) {
      atomAddF(&pb[bb], 1.f);
      float sq = 0.f;
#pragma unroll
      for (int e = 0; e < E; ++e) {
        const float d = mean[bb][i][e] - mean[bb][j][e];
        sq += d * d;
      }
      const float dn = sq > 0.f ? sqrtf(sq) : 0.f;
      const float h = 3.0f - dn;   // 2*DELTA_D - d
      if (h > 0.f) atomAddF(&db[bb], h * h);
    }
  }
  __syncthreads();

  if (t == 0) {
    float sv = 0.f, sd = 0.f, sr = 0.f, svalid = 0.f;
    for (int bb = 0; bb < B; ++bb) {
      const float ni  = nb[bb];
      const float nim = ni > 1.f ? ni : 1.f;
      const float var_b = vb[bb] / nim;
      const float reg_b = rb[bb] / nim;
      const float npm   = pb[bb] > 1.f ? pb[bb] : 1.f;
      const float dist_b = (ni > 1.f) ? (db[bb] / npm) : 0.f;
      const float valid  = ni > 0.f ? 1.f : 0.f;
      sv += var_b * valid;
      sd += dist_b * valid;
      sr += reg_b * valid;
      svalid += valid;
    }
    const float vs = svalid > 1.f ? svalid : 1.f;
    const float var = sv / vs, dist = sd / vs, reg = sr / vs;
    out[0] = var + dist + 0.001f * reg;
    out[1] = var;
    out[2] = dist;
    out[3] = reg;
  }
}

extern "C" void kernel_launch(void* const* d_in, const int* in_sizes, int n_in,
                              void* d_out, int out_size, void* d_ws, size_t ws_size,
                              hipStream_t stream) {
  const float* emb  = (const float*)d_in[0];
  const int*   mask = (const int*)d_in[1];
  float* out = (float*)d_out;

  float* sums    = (float*)d_ws;                                        // B*KI*E
  int*   counts  = (int*)((char*)d_ws + (size_t)B * KI * E * 4);        // B*KI
  float* var_per = (float*)((char*)d_ws + (size_t)(B * KI * E + B * KI) * 4);  // B*KI

  hipMemsetAsync(d_ws, 0, (size_t)(B * KI * E + 2 * B * KI) * 4, stream);

  pass1_kernel<<<dim3(P1_BPI, B), BLK, 0, stream>>>(emb, mask, sums, counts);
  pass2_kernel<<<dim3(P2_BPI, B), BLK, 0, stream>>>(emb, mask, sums, counts, var_per);
  final_kernel<<<1, BLK, 0, stream>>>(sums, counts, var_per, out);
}

// Round 3
// 254.872 us; speedup vs baseline: 1.5331x; 1.5283x over previous
//
#include <hip/hip_runtime.h>
#include <math.h>

// DiscriminativeLoss: embeddings (8,16,512,512) f32, instance_masks (8,512,512) i32 in [0,33)
// out: 4 f32 [total, var, dist, reg]
//
// Pass1 = one-hot MFMA GEMM (no LDS atomics: gfx950 ds_add measured ~215cyc/inst).
// gsum layout: [B][32][17]  (cols 0..15 = channel sums, col 16 = count), segs 1..32.

#define B 8
#define E 16
#define HW (512*512)
#define BLK 256
#define P1_BPI 128             // blocks per image; 4 waves/block, 512 px/wave, 32 K=16 tiles
#define P2_BPI 64              // blocks per image; 1024 float4-groups/block, 4 iters/thread
#define P2_VPB (HW / 4 / P2_BPI)

typedef __attribute__((ext_vector_type(8)))  short short8;
typedef __attribute__((ext_vector_type(16))) float floatx16;

__device__ __forceinline__ float atomAddF(float* p, float v) {
  return unsafeAtomicAdd(p, v);
}

__device__ __forceinline__ short f2bf(float f) {   // RNE float->bf16 (no NaN inputs)
  unsigned u = __float_as_uint(f);
  u = u + 0x7FFF + ((u >> 16) & 1);
  return (short)(u >> 16);
}

// ---------------- Pass 1: segment sums+counts via one-hot MFMA ----------------
__global__ __launch_bounds__(BLK) void pass1_kernel(
    const float* __restrict__ emb, const int* __restrict__ mask,
    float* __restrict__ gsum /*[B][32][17]*/) {
  __shared__ float lred[4][32][33];
  const int b    = blockIdx.y;
  const int t    = threadIdx.x;
  const int lane = t & 63;
  const int wv   = __builtin_amdgcn_readfirstlane(t >> 6);
  const int n    = lane & 31;        // A: row m (segment id-1). B/D: col n (channel).
  const int h    = lane >> 5;        // k-half: k = 8*h + e
  const int myid = n + 1;

  const int ppw    = HW / (P1_BPI * 4);          // 512 pixels per wave
  const int base   = (blockIdx.x * 4 + wv) * ppw;
  const int ntiles = ppw / 16;                   // 32

  const int*   __restrict__ mb = mask + (size_t)b * HW + base;
  const float* __restrict__ pl = emb + ((size_t)b * E + (n & 15)) * HW + base + 8 * h;

  floatx16 acc;
#pragma unroll
  for (int i = 0; i < 16; ++i) acc[i] = 0.f;

#pragma unroll 2
  for (int tl = 0; tl < ntiles; ++tl) {
    // 16 mask values, wave-uniform address (base uniform via readfirstlane)
    const int4 m0 = ((const int4*)(mb + tl * 16))[0];
    const int4 m1 = ((const int4*)(mb + tl * 16))[1];
    const int4 m2 = ((const int4*)(mb + tl * 16))[2];
    const int4 m3 = ((const int4*)(mb + tl * 16))[3];

    // B fragment: B[k][n] = emb[n][p_k] (n<16), 1.0 (n==16: counts), 0 (n>16)
    short8 bf;
    if (n < 16) {
      const float4 f0 = ((const float4*)(pl + tl * 16))[0];
      const float4 f1 = ((const float4*)(pl + tl * 16))[1];
      bf[0] = f2bf(f0.x); bf[1] = f2bf(f0.y); bf[2] = f2bf(f0.z); bf[3] = f2bf(f0.w);
      bf[4] = f2bf(f1.x); bf[5] = f2bf(f1.y); bf[6] = f2bf(f1.z); bf[7] = f2bf(f1.w);
    } else if (n == 16) {
      const short one = (short)0x3F80;
      bf[0]=one; bf[1]=one; bf[2]=one; bf[3]=one; bf[4]=one; bf[5]=one; bf[6]=one; bf[7]=one;
    } else {
      bf[0]=0; bf[1]=0; bf[2]=0; bf[3]=0; bf[4]=0; bf[5]=0; bf[6]=0; bf[7]=0;
    }

    // A fragment: one-hot A[m][k] = (mask[p_k] == m+1); mask==0 -> all rows 0
    const int4 ma = h ? m2 : m0;
    const int4 mc = h ? m3 : m1;
    short8 af;
    af[0] = (ma.x == myid) ? (short)0x3F80 : (short)0;
    af[1] = (ma.y == myid) ? (short)0x3F80 : (short)0;
    af[2] = (ma.z == myid) ? (short)0x3F80 : (short)0;
    af[3] = (ma.w == myid) ? (short)0x3F80 : (short)0;
    af[4] = (mc.x == myid) ? (short)0x3F80 : (short)0;
    af[5] = (mc.y == myid) ? (short)0x3F80 : (short)0;
    af[6] = (mc.z == myid) ? (short)0x3F80 : (short)0;
    af[7] = (mc.w == myid) ? (short)0x3F80 : (short)0;

    acc = __builtin_amdgcn_mfma_f32_32x32x16_bf16(af, bf, acc, 0, 0, 0);
  }

  // C/D layout (verified m74/m101): col = lane&31, row = (reg&3)+8*(reg>>2)+4*(lane>>5)
#pragma unroll
  for (int r = 0; r < 16; ++r) {
    const int row = (r & 3) + 8 * (r >> 2) + 4 * h;
    lred[wv][row][n] = acc[r];
  }
  __syncthreads();

  for (int i = t; i < 32 * 32; i += BLK) {
    const int row = i >> 5, col = i & 31;
    if (col < 17) {
      const float s = lred[0][row][col] + lred[1][row][col]
                    + lred[2][row][col] + lred[3][row][col];
      atomAddF(&gsum[((size_t)b * 32 + row) * 17 + col], s);
    }
  }
}

// ---------------- Pass 2: per-pixel hinge, per-lane private LDS slots ----------------
__global__ __launch_bounds__(BLK) void pass2_kernel(
    const float* __restrict__ emb, const int* __restrict__ mask,
    const float* __restrict__ gsum, float* __restrict__ var_per /*[B][32]*/) {
  __shared__ float mean[33][20];       // row 0 = zeros (id==0 discarded)
  __shared__ float slots[4][64][33];   // [wave][lane][id] — no atomics needed
  const int b    = blockIdx.y;
  const int t    = threadIdx.x;
  const int lane = t & 63;
  const int wv   = t >> 6;

  for (int i = t; i < 33 * 20; i += BLK) {
    const int k = i / 20, e = i - k * 20;
    float m = 0.f;
    if (k >= 1 && e < E) {
      const float c  = gsum[((size_t)b * 32 + (k - 1)) * 17 + 16];
      const float cc = c > 1.f ? c : 1.f;
      m = gsum[((size_t)b * 32 + (k - 1)) * 17 + e] / cc;
    }
    mean[k][e] = m;
  }
  for (int i = t; i < 4 * 64 * 33; i += BLK) (&slots[0][0][0])[i] = 0.f;
  __syncthreads();

  const int4*  __restrict__ maskv = (const int4*)(mask + (size_t)b * HW);
  const float* __restrict__ embb  = emb + (size_t)b * E * HW;
  float* mys = &slots[wv][lane][0];
  const int v0 = blockIdx.x * P2_VPB;

#pragma unroll 1
  for (int v = v0 + t; v < v0 + P2_VPB; v += BLK) {
    const int4 id = maskv[v];
    float d0 = 0.f, d1 = 0.f, d2 = 0.f, d3 = 0.f;
#pragma unroll
    for (int j = 0; j < 4; ++j) {
      const float4 x0 = ((const float4*)(embb + (size_t)(4 * j + 0) * HW))[v];
      const float4 x1 = ((const float4*)(embb + (size_t)(4 * j + 1) * HW))[v];
      const float4 x2 = ((const float4*)(embb + (size_t)(4 * j + 2) * HW))[v];
      const float4 x3 = ((const float4*)(embb + (size_t)(4 * j + 3) * HW))[v];
      const float4 m0 = *(const float4*)&mean[id.x][4 * j];
      const float4 m1 = *(const float4*)&mean[id.y][4 * j];
      const float4 m2 = *(const float4*)&mean[id.z][4 * j];
      const float4 m3 = *(const float4*)&mean[id.w][4 * j];
      float u;
      u = x0.x - m0.x; d0 += u * u;  u = x1.x - m0.y; d0 += u * u;
      u = x2.x - m0.z; d0 += u * u;  u = x3.x - m0.w; d0 += u * u;
      u = x0.y - m1.x; d1 += u * u;  u = x1.y - m1.y; d1 += u * u;
      u = x2.y - m1.z; d1 += u * u;  u = x3.y - m1.w; d1 += u * u;
      u = x0.z - m2.x; d2 += u * u;  u = x1.z - m2.y; d2 += u * u;
      u = x2.z - m2.z; d2 += u * u;  u = x3.z - m2.w; d2 += u * u;
      u = x0.w - m3.x; d3 += u * u;  u = x1.w - m3.y; d3 += u * u;
      u = x2.w - m3.z; d3 += u * u;  u = x3.w - m3.w; d3 += u * u;
    }
    float hh;
    hh = fmaxf(sqrtf(d0) - 0.5f, 0.f); mys[id.x] += hh * hh;
    hh = fmaxf(sqrtf(d1) - 0.5f, 0.f); mys[id.y] += hh * hh;
    hh = fmaxf(sqrtf(d2) - 0.5f, 0.f); mys[id.z] += hh * hh;
    hh = fmaxf(sqrtf(d3) - 0.5f, 0.f); mys[id.w] += hh * hh;
  }
  __syncthreads();

  // reduce slots: waves -> plane 0, then lanes
  for (int i = t; i < 64 * 33; i += BLK) {
    const int l = i / 33, k = i - l * 33;
    slots[0][l][k] += slots[1][l][k] + slots[2][l][k] + slots[3][l][k];
  }
  __syncthreads();
  if (t >= 1 && t < 33) {
    float s = 0.f;
    for (int l = 0; l < 64; ++l) s += slots[0][l][t];
    atomAddF(&var_per[b * 32 + (t - 1)], s);
  }
}

// ---------------- Final: losses from gsum/var_per ----------------
__global__ __launch_bounds__(BLK) void final_kernel(
    const float* __restrict__ gsum, const float* __restrict__ var_per,
    float* __restrict__ out) {
  __shared__ float mean[B][32][E];   // 16 KB
  __shared__ float cnts[B][32];
  __shared__ float vb[B], rb[B], db[B], pb[B], nb[B];
  const int t = threadIdx.x;

  if (t < B) { vb[t] = 0.f; rb[t] = 0.f; db[t] = 0.f; pb[t] = 0.f; nb[t] = 0.f; }
  {
    const int bb = t >> 5, k = t & 31;           // 256 threads = B*32
    const float c  = gsum[((size_t)bb * 32 + k) * 17 + 16];
    const float cc = c > 1.f ? c : 1.f;
    cnts[bb][k] = c;
#pragma unroll
    for (int e = 0; e < E; ++e)
      mean[bb][k][e] = gsum[((size_t)bb * 32 + k) * 17 + e] / cc;
  }
  __syncthreads();

  {
    const int bb = t >> 5, k = t & 31;
    const float c = cnts[bb][k];
    if (c > 0.5f) {
      atomAddF(&nb[bb], 1.f);
      atomAddF(&vb[bb], var_per[bb * 32 + k] / c);
      float sq = 0.f;
#pragma unroll
      for (int e = 0; e < E; ++e) { const float m = mean[bb][k][e]; sq += m * m; }
      atomAddF(&rb[bb], sq > 0.f ? sqrtf(sq) : 0.f);
    }
  }
  __syncthreads();

  for (int idx = t; idx < B * 32 * 32; idx += BLK) {
    const int bb = idx >> 10;
    const int p  = idx & 1023;
    const int i  = p >> 5;
    const int j  = p & 31;
    if (i < j && cnts[bb][i] > 0.5f && cnts[bb][j] > 0.5f) {
      atomAddF(&pb[bb], 1.f);
      float sq = 0.f;
#pragma unroll
      for (int e = 0; e < E; ++e) {
        const float d = mean[bb][i][e] - mean[bb][j][e];
        sq += d * d;
      }
      const float dn = sq > 0.f ? sqrtf(sq) : 0.f;
      const float hh = 3.0f - dn;    // 2*DELTA_D - d
      if (hh > 0.f) atomAddF(&db[bb], hh * hh);
    }
  }
  __syncthreads();

  if (t == 0) {
    float sv = 0.f, sd = 0.f, sr = 0.f, svalid = 0.f;
    for (int bb = 0; bb < B; ++bb) {
      const float ni  = nb[bb];
      const float nim = ni > 1.f ? ni : 1.f;
      const float var_b = vb[bb] / nim;
      const float reg_b = rb[bb] / nim;
      const float npm   = pb[bb] > 1.f ? pb[bb] : 1.f;
      const float dist_b = (ni > 1.f) ? (db[bb] / npm) : 0.f;
      const float valid  = ni > 0.f ? 1.f : 0.f;
      sv += var_b * valid;
      sd += dist_b * valid;
      sr += reg_b * valid;
      svalid += valid;
    }
    const float vs = svalid > 1.f ? svalid : 1.f;
    const float var = sv / vs, dist = sd / vs, reg = sr / vs;
    out[0] = var + dist + 0.001f * reg;
    out[1] = var;
    out[2] = dist;
    out[3] = reg;
  }
}

extern "C" void kernel_launch(void* const* d_in, const int* in_sizes, int n_in,
                              void* d_out, int out_size, void* d_ws, size_t ws_size,
                              hipStream_t stream) {
  const float* emb  = (const float*)d_in[0];
  const int*   mask = (const int*)d_in[1];
  float* out = (float*)d_out;

  float* gsum    = (float*)d_ws;                                  // B*32*17 = 4352 floats
  float* var_per = (float*)((char*)d_ws + (size_t)B * 32 * 17 * 4);  // B*32

  hipMemsetAsync(d_ws, 0, (size_t)(B * 32 * 17 + B * 32) * 4, stream);

  pass1_kernel<<<dim3(P1_BPI, B), BLK, 0, stream>>>(emb, mask, gsum);
  pass2_kernel<<<dim3(P2_BPI, B), BLK, 0, stream>>>(emb, mask, gsum, var_per);
  final_kernel<<<1, BLK, 0, stream>>>(gsum, var_per, out);
}

// Round 4
// 251.663 us; speedup vs baseline: 1.5527x; 1.0128x over previous
//
#include <hip/hip_runtime.h>
#include <math.h>

// DiscriminativeLoss: embeddings (8,16,512,512) f32, instance_masks (8,512,512) i32 in [0,33)
// out: 4 f32 [total, var, dist, reg]
//
// Pass1 = one-hot MFMA GEMM (gfx950 ds_add measured ~54cyc/wave-inst -> avoid per-pixel atomics).
// gsum layout: [B][32][17]  (cols 0..15 = channel sums, col 16 = count), segs 1..32.

#define B 8
#define E 16
#define HW (512*512)
#define BLK 256
#define P1_BPI 128             // 1024 blocks; 4 waves/block, 512 px/wave, 32 K=16 tiles
#define P2_BPI 128             // 1024 blocks; 512 float4-groups/block, 2 iters/thread
#define P2_VPB (HW / 4 / P2_BPI)

typedef __attribute__((ext_vector_type(8)))  short short8;
typedef __attribute__((ext_vector_type(16))) float floatx16;

__device__ __forceinline__ float atomAddF(float* p, float v) {
  return unsafeAtomicAdd(p, v);
}

// pack trunc-bf16(a) | trunc-bf16(b)<<16 in ONE v_perm_b32
// D.b0=sel2->a.b2, D.b1=sel3->a.b3, D.b2=sel6->b.b2, D.b3=sel7->b.b3
__device__ __forceinline__ unsigned pack_bf(float a, float b) {
  return __builtin_amdgcn_perm(__float_as_uint(b), __float_as_uint(a), 0x07060302u);
}

struct Tile { int4 ma, mb_, mc, md; float4 f0, f1; };

__device__ __forceinline__ void load_tile(Tile& T, const int* __restrict__ mb,
                                          const float* __restrict__ pl, int tl, bool ld_emb) {
  const int4* mp = (const int4*)(mb + tl * 16);
  T.ma = mp[0]; T.mb_ = mp[1]; T.mc = mp[2]; T.md = mp[3];
  if (ld_emb) {
    T.f0 = ((const float4*)(pl + tl * 16))[0];
    T.f1 = ((const float4*)(pl + tl * 16))[1];
  }
}

// ---------------- Pass 1: segment sums+counts via one-hot MFMA ----------------
__global__ __launch_bounds__(BLK) void pass1_kernel(
    const float* __restrict__ emb, const int* __restrict__ mask,
    float* __restrict__ gsum /*[B][32][17]*/) {
  __shared__ float lred[4][32][33];
  const int b    = blockIdx.y;
  const int t    = threadIdx.x;
  const int lane = t & 63;
  const int wv   = __builtin_amdgcn_readfirstlane(t >> 6);
  const int n    = lane & 31;        // A: row m (segment id-1). B/D: col n (channel).
  const int h    = lane >> 5;        // k-half: k = 8*h + j
  const int myid = n + 1;
  const bool ld  = (n < 16);

  const int ppw    = HW / (P1_BPI * 4);          // 512 pixels per wave
  const int base   = (blockIdx.x * 4 + wv) * ppw;
  const int ntiles = ppw / 16;                   // 32

  const int*   __restrict__ mb = mask + (size_t)b * HW + base;
  const float* __restrict__ pl = emb + ((size_t)b * E + (n & 15)) * HW + base + 8 * h;

  floatx16 acc;
#pragma unroll
  for (int i = 0; i < 16; ++i) acc[i] = 0.f;

  Tile cur, nxt;
  load_tile(cur, mb, pl, 0, ld);

#pragma unroll 2
  for (int tl = 0; tl < ntiles; ++tl) {
    if (tl + 1 < ntiles) load_tile(nxt, mb, pl, tl + 1, ld);  // prefetch

    // B fragment: B[k][n] = emb[n][p_k] (n<16), 1.0 (n==16: counts), 0 (n>16)
    short8 bf;
    if (ld) {
      union { uint4 u; short8 s; } cv;
      cv.u.x = pack_bf(cur.f0.x, cur.f0.y);
      cv.u.y = pack_bf(cur.f0.z, cur.f0.w);
      cv.u.z = pack_bf(cur.f1.x, cur.f1.y);
      cv.u.w = pack_bf(cur.f1.z, cur.f1.w);
      bf = cv.s;
    } else if (n == 16) {
      const short one = (short)0x3F80;
      bf[0]=one; bf[1]=one; bf[2]=one; bf[3]=one; bf[4]=one; bf[5]=one; bf[6]=one; bf[7]=one;
    } else {
      bf[0]=0; bf[1]=0; bf[2]=0; bf[3]=0; bf[4]=0; bf[5]=0; bf[6]=0; bf[7]=0;
    }

    // A fragment: one-hot A[m][k] = (mask[p_k] == m+1); mask==0 -> all rows 0
    const int4 A0 = h ? cur.mc : cur.ma;
    const int4 A1 = h ? cur.md : cur.mb_;
    short8 af;
    af[0] = (A0.x == myid) ? (short)0x3F80 : (short)0;
    af[1] = (A0.y == myid) ? (short)0x3F80 : (short)0;
    af[2] = (A0.z == myid) ? (short)0x3F80 : (short)0;
    af[3] = (A0.w == myid) ? (short)0x3F80 : (short)0;
    af[4] = (A1.x == myid) ? (short)0x3F80 : (short)0;
    af[5] = (A1.y == myid) ? (short)0x3F80 : (short)0;
    af[6] = (A1.z == myid) ? (short)0x3F80 : (short)0;
    af[7] = (A1.w == myid) ? (short)0x3F80 : (short)0;

    acc = __builtin_amdgcn_mfma_f32_32x32x16_bf16(af, bf, acc, 0, 0, 0);
    cur = nxt;
  }

  // C/D layout (verified m74/m101): col = lane&31, row = (reg&3)+8*(reg>>2)+4*(lane>>5)
#pragma unroll
  for (int r = 0; r < 16; ++r) {
    const int row = (r & 3) + 8 * (r >> 2) + 4 * h;
    lred[wv][row][n] = acc[r];
  }
  __syncthreads();

  for (int i = t; i < 32 * 32; i += BLK) {
    const int row = i >> 5, col = i & 31;
    if (col < 17) {
      const float s = lred[0][row][col] + lred[1][row][col]
                    + lred[2][row][col] + lred[3][row][col];
      atomAddF(&gsum[((size_t)b * 32 + row) * 17 + col], s);
    }
  }
}

// ---------------- Pass 2: per-pixel hinge( ||x - mean[id]|| ) ----------------
__global__ __launch_bounds__(BLK) void pass2_kernel(
    const float* __restrict__ emb, const int* __restrict__ mask,
    const float* __restrict__ gsum, float* __restrict__ var_per /*[B][32]*/) {
  // XOR-swizzled means: logical chunk j of row k lives at physical slot (j+k)&3.
  // bank-group(k, j) = (4k + (j+k)&3) mod 8 -> rows 0..7 hit distinct groups for any j.
  __shared__ float mean4[33][4][4];   // row 0 = zeros (id==0 discarded)
  __shared__ float lvar[33][8];
  const int b = blockIdx.y;
  const int t = threadIdx.x;
  const int c = t & 7;

  for (int i = t; i < 33 * 16; i += BLK) {
    const int k = i >> 4, e = i & 15;
    float m = 0.f;
    if (k >= 1) {
      const float cnt = gsum[((size_t)b * 32 + (k - 1)) * 17 + 16];
      const float cc  = cnt > 1.f ? cnt : 1.f;
      m = gsum[((size_t)b * 32 + (k - 1)) * 17 + e] / cc;
    }
    const int j = e >> 2;
    mean4[k][(j + k) & 3][e & 3] = m;
  }
  for (int i = t; i < 33 * 8; i += BLK) (&lvar[0][0])[i] = 0.f;
  __syncthreads();

  const int4*  __restrict__ maskv = (const int4*)(mask + (size_t)b * HW);
  const float* __restrict__ embb  = emb + (size_t)b * E * HW;
  const int v0 = blockIdx.x * P2_VPB;

#pragma unroll 1
  for (int v = v0 + t; v < v0 + P2_VPB; v += BLK) {
    const int4 id = maskv[v];
    float4 x[E];                      // all global loads in flight first
#pragma unroll
    for (int e = 0; e < E; ++e) x[e] = ((const float4*)(embb + (size_t)e * HW))[v];

    float d0 = 0.f, d1 = 0.f, d2 = 0.f, d3 = 0.f;
#pragma unroll
    for (int j = 0; j < 4; ++j) {
      const float4 m0 = *(const float4*)&mean4[id.x][(j + id.x) & 3][0];
      const float4 m1 = *(const float4*)&mean4[id.y][(j + id.y) & 3][0];
      const float4 m2 = *(const float4*)&mean4[id.z][(j + id.z) & 3][0];
      const float4 m3 = *(const float4*)&mean4[id.w][(j + id.w) & 3][0];
      const float4 a0 = x[4 * j + 0], a1 = x[4 * j + 1];
      const float4 a2 = x[4 * j + 2], a3 = x[4 * j + 3];
      float u;
      u = a0.x - m0.x; d0 += u * u;  u = a1.x - m0.y; d0 += u * u;
      u = a2.x - m0.z; d0 += u * u;  u = a3.x - m0.w; d0 += u * u;
      u = a0.y - m1.x; d1 += u * u;  u = a1.y - m1.y; d1 += u * u;
      u = a2.y - m1.z; d1 += u * u;  u = a3.y - m1.w; d1 += u * u;
      u = a0.z - m2.x; d2 += u * u;  u = a1.z - m2.y; d2 += u * u;
      u = a2.z - m2.z; d2 += u * u;  u = a3.z - m2.w; d2 += u * u;
      u = a0.w - m3.x; d3 += u * u;  u = a1.w - m3.y; d3 += u * u;
      u = a2.w - m3.z; d3 += u * u;  u = a3.w - m3.w; d3 += u * u;
    }
    float hh;  // branch-free hinge; id==0 lands in trash row 0
    hh = fmaxf(sqrtf(d0) - 0.5f, 0.f); atomAddF(&lvar[id.x][c], hh * hh);
    hh = fmaxf(sqrtf(d1) - 0.5f, 0.f); atomAddF(&lvar[id.y][c], hh * hh);
    hh = fmaxf(sqrtf(d2) - 0.5f, 0.f); atomAddF(&lvar[id.z][c], hh * hh);
    hh = fmaxf(sqrtf(d3) - 0.5f, 0.f); atomAddF(&lvar[id.w][c], hh * hh);
  }
  __syncthreads();

  if (t >= 1 && t < 33) {
    float s = 0.f;
#pragma unroll
    for (int cc = 0; cc < 8; ++cc) s += lvar[t][cc];
    atomAddF(&var_per[b * 32 + (t - 1)], s);
  }
}

// ---------------- Final: losses from gsum/var_per ----------------
__global__ __launch_bounds__(BLK) void final_kernel(
    const float* __restrict__ gsum, const float* __restrict__ var_per,
    float* __restrict__ out) {
  __shared__ float mean[B][32][E];   // 16 KB
  __shared__ float cnts[B][32];
  __shared__ float vb[B], rb[B], db[B], pb[B], nb[B];
  const int t = threadIdx.x;

  if (t < B) { vb[t] = 0.f; rb[t] = 0.f; db[t] = 0.f; pb[t] = 0.f; nb[t] = 0.f; }
  {
    const int bb = t >> 5, k = t & 31;           // 256 threads = B*32
    const float c  = gsum[((size_t)bb * 32 + k) * 17 + 16];
    const float cc = c > 1.f ? c : 1.f;
    cnts[bb][k] = c;
#pragma unroll
    for (int e = 0; e < E; ++e)
      mean[bb][k][e] = gsum[((size_t)bb * 32 + k) * 17 + e] / cc;
  }
  __syncthreads();

  {
    const int bb = t >> 5, k = t & 31;
    const float c = cnts[bb][k];
    if (c > 0.5f) {
      atomAddF(&nb[bb], 1.f);
      atomAddF(&vb[bb], var_per[bb * 32 + k] / c);
      float sq = 0.f;
#pragma unroll
      for (int e = 0; e < E; ++e) { const float m = mean[bb][k][e]; sq += m * m; }
      atomAddF(&rb[bb], sq > 0.f ? sqrtf(sq) : 0.f);
    }
  }
  __syncthreads();

  for (int idx = t; idx < B * 32 * 32; idx += BLK) {
    const int bb = idx >> 10;
    const int p  = idx & 1023;
    const int i  = p >> 5;
    const int j  = p & 31;
    if (i < j && cnts[bb][i] > 0.5f && cnts[bb][j] > 0.5f) {
      atomAddF(&pb[bb], 1.f);
      float sq = 0.f;
#pragma unroll
      for (int e = 0; e < E; ++e) {
        const float d = mean[bb][i][e] - mean[bb][j][e];
        sq += d * d;
      }
      const float dn = sq > 0.f ? sqrtf(sq) : 0.f;
      const float hh = 3.0f - dn;    // 2*DELTA_D - d
      if (hh > 0.f) atomAddF(&db[bb], hh * hh);
    }
  }
  __syncthreads();

  if (t == 0) {
    float sv = 0.f, sd = 0.f, sr = 0.f, svalid = 0.f;
    for (int bb = 0; bb < B; ++bb) {
      const float ni  = nb[bb];
      const float nim = ni > 1.f ? ni : 1.f;
      const float var_b = vb[bb] / nim;
      const float reg_b = rb[bb] / nim;
      const float npm   = pb[bb] > 1.f ? pb[bb] : 1.f;
      const float dist_b = (ni > 1.f) ? (db[bb] / npm) : 0.f;
      const float valid  = ni > 0.f ? 1.f : 0.f;
      sv += var_b * valid;
      sd += dist_b * valid;
      sr += reg_b * valid;
      svalid += valid;
    }
    const float vs = svalid > 1.f ? svalid : 1.f;
    const float var = sv / vs, dist = sd / vs, reg = sr / vs;
    out[0] = var + dist + 0.001f * reg;
    out[1] = var;
    out[2] = dist;
    out[3] = reg;
  }
}

extern "C" void kernel_launch(void* const* d_in, const int* in_sizes, int n_in,
                              void* d_out, int out_size, void* d_ws, size_t ws_size,
                              hipStream_t stream) {
  const float* emb  = (const float*)d_in[0];
  const int*   mask = (const int*)d_in[1];
  float* out = (float*)d_out;

  float* gsum    = (float*)d_ws;                                     // B*32*17 floats
  float* var_per = (float*)((char*)d_ws + (size_t)B * 32 * 17 * 4);  // B*32

  hipMemsetAsync(d_ws, 0, (size_t)(B * 32 * 17 + B * 32) * 4, stream);

  pass1_kernel<<<dim3(P1_BPI, B), BLK, 0, stream>>>(emb, mask, gsum);
  pass2_kernel<<<dim3(P2_BPI, B), BLK, 0, stream>>>(emb, mask, gsum, var_per);
  final_kernel<<<1, BLK, 0, stream>>>(gsum, var_per, out);
}

// Round 6
// 250.425 us; speedup vs baseline: 1.5604x; 1.0049x over previous
//
#include <hip/hip_runtime.h>
#include <math.h>

// DiscriminativeLoss: embeddings (8,16,512,512) f32, instance_masks (8,512,512) i32 in [0,33)
// out: 4 f32 [total, var, dist, reg]
//
// Pass1 = one-hot MFMA GEMM, 4-deep register ring pipeline (no copy-chain waits).
//         Mask staged in LDS as native int4 (16B-aligned: b128 LDS ops trap on misalign).
// Pass2 = weighted-hinge register accumulation: var = sum_p h_p^2 / cnt[id_p]
//         (no per-pixel LDS atomics; one global atomic per block).
// gsum layout: [B][32][17]  (cols 0..15 = channel sums, col 16 = count), segs 1..32.

#define B 8
#define E 16
#define HW (512*512)
#define BLK 256
#define P1_BPI 128             // 1024 blocks; 4 waves/block, 512 px/wave, 32 K=16 tiles
#define P2_BPI 128             // 1024 blocks; 512 float4-groups/block, 2 iters/thread
#define P2_VPB (HW / 4 / P2_BPI)

typedef __attribute__((ext_vector_type(8)))  short short8;
typedef __attribute__((ext_vector_type(16))) float floatx16;

__device__ __forceinline__ float atomAddF(float* p, float v) {
  return unsafeAtomicAdd(p, v);
}

// pack trunc-bf16(a) | trunc-bf16(b)<<16 in ONE v_perm_b32
__device__ __forceinline__ unsigned pack_bf(float a, float b) {
  return __builtin_amdgcn_perm(__float_as_uint(b), __float_as_uint(a), 0x07060302u);
}

// ---------------- Pass 1: segment sums+counts via one-hot MFMA ----------------
__global__ __launch_bounds__(BLK) void pass1_kernel(
    const float* __restrict__ emb, const int* __restrict__ mask,
    float* __restrict__ gsum /*[B][32][17]*/) {
  __shared__ int4 mstage[4][128];                    // per-wave mask stage (8 KB), native 16B align
  __shared__ __align__(16) float lred[4][32][33];    // cross-wave reduce (16.9 KB)
  const int b    = blockIdx.y;
  const int t    = threadIdx.x;
  const int lane = t & 63;
  const int wv   = __builtin_amdgcn_readfirstlane(t >> 6);
  const int n    = lane & 31;        // A: row m (segment id-1). B/D: col n (channel).
  const int h    = lane >> 5;        // k-half: k = 8*h + j
  const int myid = n + 1;
  const bool ld  = (n < 16);

  const int ppw    = HW / (P1_BPI * 4);          // 512 pixels per wave
  const int ntiles = ppw / 16;                   // 32
  const int base   = (blockIdx.x * 4 + wv) * ppw;

  // ---- stage this wave's 512 mask values into LDS (2 coalesced int4 loads) ----
  {
    const int4* __restrict__ mg = (const int4*)(mask + (size_t)b * HW + base);
    mstage[wv][lane]      = mg[lane];
    mstage[wv][64 + lane] = mg[64 + lane];
  }
  __syncthreads();

  const float* __restrict__ pl = emb + ((size_t)b * E + (n & 15)) * HW + base + 8 * h;

  floatx16 acc;
#pragma unroll
  for (int i = 0; i < 16; ++i) acc[i] = 0.f;

  // ---- 4-deep ring: tiles tl..tl+3 always in flight ----
  float4 fb[4][2];
#pragma unroll
  for (int u = 0; u < 4; ++u) {
    if (ld) {
      fb[u][0] = ((const float4*)(pl + u * 16))[0];
      fb[u][1] = ((const float4*)(pl + u * 16))[1];
    }
  }

  for (int tl4 = 0; tl4 < ntiles; tl4 += 4) {
#pragma unroll
    for (int u = 0; u < 4; ++u) {
      const int tl = tl4 + u;

      // masks: 2 broadcast b128 reads (one address per k-half -> conflict-free)
      const int4 A0 = mstage[wv][tl * 4 + 2 * h];
      const int4 A1 = mstage[wv][tl * 4 + 2 * h + 1];

      short8 af;
      af[0] = (A0.x == myid) ? (short)0x3F80 : (short)0;
      af[1] = (A0.y == myid) ? (short)0x3F80 : (short)0;
      af[2] = (A0.z == myid) ? (short)0x3F80 : (short)0;
      af[3] = (A0.w == myid) ? (short)0x3F80 : (short)0;
      af[4] = (A1.x == myid) ? (short)0x3F80 : (short)0;
      af[5] = (A1.y == myid) ? (short)0x3F80 : (short)0;
      af[6] = (A1.z == myid) ? (short)0x3F80 : (short)0;
      af[7] = (A1.w == myid) ? (short)0x3F80 : (short)0;

      short8 bf;
      if (ld) {
        union { uint4 u4; short8 s; } cv;
        cv.u4.x = pack_bf(fb[u][0].x, fb[u][0].y);
        cv.u4.y = pack_bf(fb[u][0].z, fb[u][0].w);
        cv.u4.z = pack_bf(fb[u][1].x, fb[u][1].y);
        cv.u4.w = pack_bf(fb[u][1].z, fb[u][1].w);
        bf = cv.s;
      } else if (n == 16) {
        const short one = (short)0x3F80;
        bf[0]=one; bf[1]=one; bf[2]=one; bf[3]=one; bf[4]=one; bf[5]=one; bf[6]=one; bf[7]=one;
      } else {
        bf[0]=0; bf[1]=0; bf[2]=0; bf[3]=0; bf[4]=0; bf[5]=0; bf[6]=0; bf[7]=0;
      }

      acc = __builtin_amdgcn_mfma_f32_32x32x16_bf16(af, bf, acc, 0, 0, 0);

      // refill slot u with tile tl+4 (no copy chain: slot indexed by constant u)
      const int tn = tl + 4;
      if (tn < ntiles && ld) {
        fb[u][0] = ((const float4*)(pl + tn * 16))[0];
        fb[u][1] = ((const float4*)(pl + tn * 16))[1];
      }
    }
  }

  // C/D layout (verified m74/m101): col = lane&31, row = (reg&3)+8*(reg>>2)+4*(lane>>5)
#pragma unroll
  for (int r = 0; r < 16; ++r) {
    const int row = (r & 3) + 8 * (r >> 2) + 4 * h;
    lred[wv][row][n] = acc[r];
  }
  __syncthreads();

  for (int i = t; i < 32 * 32; i += BLK) {
    const int row = i >> 5, col = i & 31;
    if (col < 17) {
      const float s = lred[0][row][col] + lred[1][row][col]
                    + lred[2][row][col] + lred[3][row][col];
      atomAddF(&gsum[((size_t)b * 32 + row) * 17 + col], s);
    }
  }
}

// ---------------- Pass 2: register-accumulated weighted hinge ----------------
__global__ __launch_bounds__(BLK) void pass2_kernel(
    const float* __restrict__ emb, const int* __restrict__ mask,
    const float* __restrict__ gsum, float* __restrict__ vsum /*[B]*/) {
  // Swizzle: logical chunk j of row k at physical slot (j+k+(k>>2))&3.
  // group g=(4k+slot)%8 covers all 8 bank-groups on any 8 consecutive k.
  __shared__ __align__(16) float mean4[33][4][4];   // row 0 = zeros (id==0 discarded)
  __shared__ float winv[33];          // winv[0]=0, winv[k]=1/count (0 if absent)
  __shared__ float wred[4];
  const int b = blockIdx.y;
  const int t = threadIdx.x;

  for (int i = t; i < 33 * 16; i += BLK) {
    const int k = i >> 4, e = i & 15;
    float m = 0.f;
    if (k >= 1) {
      const float cnt = gsum[((size_t)b * 32 + (k - 1)) * 17 + 16];
      const float cc  = cnt > 1.f ? cnt : 1.f;
      m = gsum[((size_t)b * 32 + (k - 1)) * 17 + e] / cc;
    }
    const int j = e >> 2;
    mean4[k][(j + k + (k >> 2)) & 3][e & 3] = m;
  }
  if (t < 33) {
    float w = 0.f;
    if (t >= 1) {
      const float cnt = gsum[((size_t)b * 32 + (t - 1)) * 17 + 16];
      w = cnt > 0.5f ? 1.f / cnt : 0.f;
    }
    winv[t] = w;
  }
  __syncthreads();

  const int4*  __restrict__ maskv = (const int4*)(mask + (size_t)b * HW);
  const float* __restrict__ embb  = emb + (size_t)b * E * HW;
  const int v0 = blockIdx.x * P2_VPB;
  float vacc = 0.f;

#pragma unroll 1
  for (int v = v0 + t; v < v0 + P2_VPB; v += BLK) {
    const int4 id = maskv[v];
    float4 x[E];                      // all 16 global loads in flight first
#pragma unroll
    for (int e = 0; e < E; ++e) x[e] = ((const float4*)(embb + (size_t)e * HW))[v];

    const int sx = id.x + (id.x >> 2);
    const int sy = id.y + (id.y >> 2);
    const int sz = id.z + (id.z >> 2);
    const int sw = id.w + (id.w >> 2);

    float d0 = 0.f, d1 = 0.f, d2 = 0.f, d3 = 0.f;
#pragma unroll
    for (int j = 0; j < 4; ++j) {
      const float4 m0 = *(const float4*)&mean4[id.x][(j + sx) & 3][0];
      const float4 m1 = *(const float4*)&mean4[id.y][(j + sy) & 3][0];
      const float4 m2 = *(const float4*)&mean4[id.z][(j + sz) & 3][0];
      const float4 m3 = *(const float4*)&mean4[id.w][(j + sw) & 3][0];
      const float4 a0 = x[4 * j + 0], a1 = x[4 * j + 1];
      const float4 a2 = x[4 * j + 2], a3 = x[4 * j + 3];
      float u;
      u = a0.x - m0.x; d0 += u * u;  u = a1.x - m0.y; d0 += u * u;
      u = a2.x - m0.z; d0 += u * u;  u = a3.x - m0.w; d0 += u * u;
      u = a0.y - m1.x; d1 += u * u;  u = a1.y - m1.y; d1 += u * u;
      u = a2.y - m1.z; d1 += u * u;  u = a3.y - m1.w; d1 += u * u;
      u = a0.z - m2.x; d2 += u * u;  u = a1.z - m2.y; d2 += u * u;
      u = a2.z - m2.z; d2 += u * u;  u = a3.z - m2.w; d2 += u * u;
      u = a0.w - m3.x; d3 += u * u;  u = a1.w - m3.y; d3 += u * u;
      u = a2.w - m3.z; d3 += u * u;  u = a3.w - m3.w; d3 += u * u;
    }
    float hh;  // weighted hinge into REGISTER; winv[0]=0 kills background
    hh = fmaxf(sqrtf(d0) - 0.5f, 0.f); vacc += hh * hh * winv[id.x];
    hh = fmaxf(sqrtf(d1) - 0.5f, 0.f); vacc += hh * hh * winv[id.y];
    hh = fmaxf(sqrtf(d2) - 0.5f, 0.f); vacc += hh * hh * winv[id.z];
    hh = fmaxf(sqrtf(d3) - 0.5f, 0.f); vacc += hh * hh * winv[id.w];
  }

  // wave shuffle-reduce -> 4 partials -> one global atomic per block
#pragma unroll
  for (int off = 32; off >= 1; off >>= 1) vacc += __shfl_down(vacc, off, 64);
  if ((t & 63) == 0) wred[t >> 6] = vacc;
  __syncthreads();
  if (t == 0) atomAddF(&vsum[b], wred[0] + wred[1] + wred[2] + wred[3]);
}

// ---------------- Final: losses from gsum/vsum ----------------
__global__ __launch_bounds__(BLK) void final_kernel(
    const float* __restrict__ gsum, const float* __restrict__ vsum,
    float* __restrict__ out) {
  __shared__ float mean[B][32][E];   // 16 KB
  __shared__ float cnts[B][32];
  __shared__ float rb[B], db[B], pb[B], nb[B];
  const int t = threadIdx.x;

  if (t < B) { rb[t] = 0.f; db[t] = 0.f; pb[t] = 0.f; nb[t] = 0.f; }
  {
    const int bb = t >> 5, k = t & 31;           // 256 threads = B*32
    const float c  = gsum[((size_t)bb * 32 + k) * 17 + 16];
    const float cc = c > 1.f ? c : 1.f;
    cnts[bb][k] = c;
#pragma unroll
    for (int e = 0; e < E; ++e)
      mean[bb][k][e] = gsum[((size_t)bb * 32 + k) * 17 + e] / cc;
  }
  __syncthreads();

  {
    const int bb = t >> 5, k = t & 31;
    const float c = cnts[bb][k];
    if (c > 0.5f) {
      atomAddF(&nb[bb], 1.f);
      float sq = 0.f;
#pragma unroll
      for (int e = 0; e < E; ++e) { const float m = mean[bb][k][e]; sq += m * m; }
      atomAddF(&rb[bb], sq > 0.f ? sqrtf(sq) : 0.f);
    }
  }
  __syncthreads();

  for (int idx = t; idx < B * 32 * 32; idx += BLK) {
    const int bb = idx >> 10;
    const int p  = idx & 1023;
    const int i  = p >> 5;
    const int j  = p & 31;
    if (i < j && cnts[bb][i] > 0.5f && cnts[bb][j] > 0.5f) {
      atomAddF(&pb[bb], 1.f);
      float sq = 0.f;
#pragma unroll
      for (int e = 0; e < E; ++e) {
        const float d = mean[bb][i][e] - mean[bb][j][e];
        sq += d * d;
      }
      const float dn = sq > 0.f ? sqrtf(sq) : 0.f;
      const float hh = 3.0f - dn;    // 2*DELTA_D - d
      if (hh > 0.f) atomAddF(&db[bb], hh * hh);
    }
  }
  __syncthreads();

  if (t == 0) {
    float sv = 0.f, sd = 0.f, sr = 0.f, svalid = 0.f;
    for (int bb = 0; bb < B; ++bb) {
      const float ni  = nb[bb];
      const float nim = ni > 1.f ? ni : 1.f;
      const float var_b = vsum[bb] / nim;
      const float reg_b = rb[bb] / nim;
      const float npm   = pb[bb] > 1.f ? pb[bb] : 1.f;
      const float dist_b = (ni > 1.f) ? (db[bb] / npm) : 0.f;
      const float valid  = ni > 0.f ? 1.f : 0.f;
      sv += var_b * valid;
      sd += dist_b * valid;
      sr += reg_b * valid;
      svalid += valid;
    }
    const float vs = svalid > 1.f ? svalid : 1.f;
    const float var = sv / vs, dist = sd / vs, reg = sr / vs;
    out[0] = var + dist + 0.001f * reg;
    out[1] = var;
    out[2] = dist;
    out[3] = reg;
  }
}

extern "C" void kernel_launch(void* const* d_in, const int* in_sizes, int n_in,
                              void* d_out, int out_size, void* d_ws, size_t ws_size,
                              hipStream_t stream) {
  const float* emb  = (const float*)d_in[0];
  const int*   mask = (const int*)d_in[1];
  float* out = (float*)d_out;

  float* gsum = (float*)d_ws;                                     // B*32*17 floats
  float* vsum = (float*)((char*)d_ws + (size_t)B * 32 * 17 * 4);  // B floats

  hipMemsetAsync(d_ws, 0, (size_t)(B * 32 * 17 + B) * 4, stream);

  pass1_kernel<<<dim3(P1_BPI, B), BLK, 0, stream>>>(emb, mask, gsum);
  pass2_kernel<<<dim3(P2_BPI, B), BLK, 0, stream>>>(emb, mask, gsum, vsum);
  final_kernel<<<1, BLK, 0, stream>>>(gsum, vsum, out);
}